// Round 2
// baseline (60162.793 us; speedup 1.0000x reference)
//
#include <hip/hip_runtime.h>
#include <hip/hip_cooperative_groups.h>

namespace cg = cooperative_groups;

#define Bb  256   // batch
#define Tt  512   // time steps
#define INx 19    // input features
#define Hh  512   // hidden
#define NWG 256   // workgroups (one unit-pair each)
#define HP  (Hh / 2)   // 256 float2 pairs per h vector

__device__ __forceinline__ float sigf(float x) {
    return 1.0f / (1.0f + __expf(-x));
}
__device__ __forceinline__ float tanhfast(float x) {
    float e = __expf(2.0f * x);
    return 1.0f - 2.0f / (e + 1.0f);   // correct saturation at +/-inf
}

// Compute gates for a unit pair from 8 accumulators, update c-state, return h pair.
__device__ __forceinline__ float2 gates(const float a[8], float& cx, float& cy) {
    const float i0 = sigf(a[0]), f0 = sigf(a[1]), g0 = tanhfast(a[2]), o0 = sigf(a[3]);
    cx = f0 * cx + i0 * g0;
    const float h0 = o0 * tanhfast(cx);
    const float i1 = sigf(a[4]), f1 = sigf(a[5]), g1 = tanhfast(a[6]), o1 = sigf(a[7]);
    cy = f1 * cy + i1 * g1;
    const float h1 = o1 * tanhfast(cy);
    return make_float2(h0, h1);
}

// Persistent cooperative kernel. WG w owns hidden units {2w, 2w+1} in BOTH
// layers; thread b owns batch b. c-states live in registers for the whole
// sequence. h stored paired-transposed: h[j2][b][2] -> coalesced float2 reads,
// each WG writes exactly its own pair. Layers fused: iteration t computes
// h1[t+1] and h2[t] between one pair of grid syncs, and the two K=512 sweeps
// over h1[t] are merged into a single loop (16 accumulators).
__global__ void __launch_bounds__(256, 1)
lstm_fused(const float* __restrict__ input,
           const float* __restrict__ l1_Wx, const float* __restrict__ l1_bx,
           const float* __restrict__ l1_Wh, const float* __restrict__ l1_bh,
           const float* __restrict__ l2_Wx, const float* __restrict__ l2_bx,
           const float* __restrict__ l2_Wh, const float* __restrict__ l2_bh,
           const float* __restrict__ fc1_W, const float* __restrict__ fc1_b,
           const float* __restrict__ fc2_W, const float* __restrict__ fc2_b,
           const float* __restrict__ fc3_W, const float* __restrict__ fc3_b,
           float* __restrict__ out, float* __restrict__ ws)
{
    cg::grid_group grid = cg::this_grid();
    const int w = blockIdx.x;    // unit-pair id
    const int b = threadIdx.x;   // batch

    float* h1_cur = ws;                 // 512 KiB each
    float* h1_alt = h1_cur + (size_t)NWG * Bb * 2;
    float* h2_cur = h1_alt + (size_t)NWG * Bb * 2;
    float* h2_alt = h2_cur + (size_t)NWG * Bb * 2;

    // Per-row weight bases (wave-uniform -> scalar loads).
    // r = u*4 + g : unit u in {0,1}, gate g in {i,f,g,o}; row = g*Hh + 2w+u.
    const float* wh1[8]; const float* wx1[8];
    const float* wx2[8]; const float* wh2[8];
    float b1[8], b2[8];
    #pragma unroll
    for (int u = 0; u < 2; ++u) {
        #pragma unroll
        for (int g = 0; g < 4; ++g) {
            const int r = u * 4 + g;
            const int row = g * Hh + (2 * w + u);
            wh1[r] = l1_Wh + (size_t)row * Hh;
            wx1[r] = l1_Wx + (size_t)row * INx;
            wx2[r] = l2_Wx + (size_t)row * Hh;
            wh2[r] = l2_Wh + (size_t)row * Hh;
            b1[r] = l1_bx[row] + l1_bh[row];
            b2[r] = l2_bx[row] + l2_bh[row];
        }
    }

    float c1x = 0.f, c1y = 0.f;   // layer-1 cell state (2 units)
    float c2x = 0.f, c2y = 0.f;   // layer-2 cell state

    // ---- prologue: h1[0] = L1(x[0], h=0) ----
    {
        float a1[8];
        #pragma unroll
        for (int r = 0; r < 8; ++r) a1[r] = b1[r];
        const float* xp = input + ((size_t)b * Tt + 0) * INx;
        #pragma unroll
        for (int i = 0; i < INx; ++i) {
            const float xv = xp[i];
            #pragma unroll
            for (int r = 0; r < 8; ++r) a1[r] += xv * wx1[r][i];
        }
        const float2 h = gates(a1, c1x, c1y);
        *reinterpret_cast<float2*>(h1_cur + ((size_t)w * Bb + b) * 2) = h;
    }
    grid.sync();

    // ---- main loop: iteration t computes h1[t+1] and h2[t] ----
    for (int t = 0; t < Tt - 1; ++t) {
        float a1[8], a2[8];
        #pragma unroll
        for (int r = 0; r < 8; ++r) { a1[r] = b1[r]; a2[r] = b2[r]; }

        // merged sweep over h1[t]: feeds L1-next (wh1) and L2-input (wx2)
        #pragma unroll 2
        for (int k2 = 0; k2 < HP; ++k2) {
            const float2 hv = *reinterpret_cast<const float2*>(h1_cur + ((size_t)k2 * Bb + b) * 2);
            #pragma unroll
            for (int r = 0; r < 8; ++r) {
                const float2 wf = *reinterpret_cast<const float2*>(wh1[r] + 2 * k2);
                a1[r] += hv.x * wf.x + hv.y * wf.y;
            }
            #pragma unroll
            for (int r = 0; r < 8; ++r) {
                const float2 wf = *reinterpret_cast<const float2*>(wx2[r] + 2 * k2);
                a2[r] += hv.x * wf.x + hv.y * wf.y;
            }
        }
        // layer-2 recurrent sweep over h2[t-1] (skip at t==0: h2[-1]=0)
        if (t > 0) {
            #pragma unroll 2
            for (int k2 = 0; k2 < HP; ++k2) {
                const float2 hv = *reinterpret_cast<const float2*>(h2_cur + ((size_t)k2 * Bb + b) * 2);
                #pragma unroll
                for (int r = 0; r < 8; ++r) {
                    const float2 wf = *reinterpret_cast<const float2*>(wh2[r] + 2 * k2);
                    a2[r] += hv.x * wf.x + hv.y * wf.y;
                }
            }
        }
        // layer-1 input projection for step t+1
        {
            const float* xp = input + ((size_t)b * Tt + (t + 1)) * INx;
            #pragma unroll
            for (int i = 0; i < INx; ++i) {
                const float xv = xp[i];
                #pragma unroll
                for (int r = 0; r < 8; ++r) a1[r] += xv * wx1[r][i];
            }
        }

        const float2 h1n = gates(a1, c1x, c1y);   // h1[t+1]
        const float2 h2n = gates(a2, c2x, c2y);   // h2[t]
        *reinterpret_cast<float2*>(h1_alt + ((size_t)w * Bb + b) * 2) = h1n;
        *reinterpret_cast<float2*>(h2_alt + ((size_t)w * Bb + b) * 2) = h2n;

        grid.sync();
        float* tmp;
        tmp = h1_cur; h1_cur = h1_alt; h1_alt = tmp;
        tmp = h2_cur; h2_cur = h2_alt; h2_alt = tmp;
    }

    // ---- epilogue: h2[511] from h1[511] (h1_cur) and h2[510] (h2_cur) ----
    {
        float a2[8];
        #pragma unroll
        for (int r = 0; r < 8; ++r) a2[r] = b2[r];
        #pragma unroll 2
        for (int k2 = 0; k2 < HP; ++k2) {
            const float2 hv = *reinterpret_cast<const float2*>(h1_cur + ((size_t)k2 * Bb + b) * 2);
            #pragma unroll
            for (int r = 0; r < 8; ++r) {
                const float2 wf = *reinterpret_cast<const float2*>(wx2[r] + 2 * k2);
                a2[r] += hv.x * wf.x + hv.y * wf.y;
            }
        }
        #pragma unroll 2
        for (int k2 = 0; k2 < HP; ++k2) {
            const float2 hv = *reinterpret_cast<const float2*>(h2_cur + ((size_t)k2 * Bb + b) * 2);
            #pragma unroll
            for (int r = 0; r < 8; ++r) {
                const float2 wf = *reinterpret_cast<const float2*>(wh2[r] + 2 * k2);
                a2[r] += hv.x * wf.x + hv.y * wf.y;
            }
        }
        const float2 h2f = gates(a2, c2x, c2y);
        *reinterpret_cast<float2*>(h2_alt + ((size_t)w * Bb + b) * 2) = h2f;
    }
    grid.sync();

    // ---- FC head: WG w handles batch w; final h2 is in h2_alt ----
    __shared__ float hh[Hh];
    __shared__ float a1s[256];
    __shared__ float a2s[128];

    {   // gather column w: thread b is pair index j2
        const float2 hv = *reinterpret_cast<const float2*>(h2_alt + ((size_t)b * Bb + w) * 2);
        hh[2 * b]     = hv.x;
        hh[2 * b + 1] = hv.y;
    }
    __syncthreads();
    {   // fc1: 256 outputs, relu
        float acc = fc1_b[b];
        const float* wr = fc1_W + (size_t)b * Hh;
        for (int i = 0; i < Hh; ++i) acc += wr[i] * hh[i];
        a1s[b] = fmaxf(acc, 0.f);
    }
    __syncthreads();
    if (b < 128) {   // fc2: 128 outputs, relu
        float acc = fc2_b[b];
        const float* wr = fc2_W + (size_t)b * 256;
        for (int i = 0; i < 256; ++i) acc += wr[i] * a1s[i];
        a2s[b] = fmaxf(acc, 0.f);
    }
    __syncthreads();
    if (b == 0) {    // fc3: single output for batch w
        float acc = fc3_b[0];
        for (int i = 0; i < 128; ++i) acc += fc3_W[i] * a2s[i];
        out[w] = acc;
    }
}

extern "C" void kernel_launch(void* const* d_in, const int* in_sizes, int n_in,
                              void* d_out, int out_size, void* d_ws, size_t ws_size,
                              hipStream_t stream)
{
    (void)in_sizes; (void)n_in; (void)out_size; (void)ws_size;

    const float* input = (const float*)d_in[0];
    const float* l1_Wx = (const float*)d_in[1];
    const float* l1_bx = (const float*)d_in[2];
    const float* l1_Wh = (const float*)d_in[3];
    const float* l1_bh = (const float*)d_in[4];
    const float* l2_Wx = (const float*)d_in[5];
    const float* l2_bx = (const float*)d_in[6];
    const float* l2_Wh = (const float*)d_in[7];
    const float* l2_bh = (const float*)d_in[8];
    const float* fc1_W = (const float*)d_in[9];
    const float* fc1_b = (const float*)d_in[10];
    const float* fc2_W = (const float*)d_in[11];
    const float* fc2_b = (const float*)d_in[12];
    const float* fc3_W = (const float*)d_in[13];
    const float* fc3_b = (const float*)d_in[14];
    float* out = (float*)d_out;
    float* ws  = (float*)d_ws;

    void* args[] = {
        &input,
        &l1_Wx, &l1_bx, &l1_Wh, &l1_bh,
        &l2_Wx, &l2_bx, &l2_Wh, &l2_bh,
        &fc1_W, &fc1_b, &fc2_W, &fc2_b, &fc3_W, &fc3_b,
        &out, &ws
    };
    hipLaunchCooperativeKernel((void*)lstm_fused, dim3(NWG), dim3(256), args, 0, stream);
}

// Round 3
// 53136.084 us; speedup vs baseline: 1.1322x; 1.1322x over previous
//
#include <hip/hip_runtime.h>
#include <hip/hip_cooperative_groups.h>

namespace cg = cooperative_groups;

#define Bb   256   // batch
#define Tt   512   // time steps
#define INx  19    // input features
#define Hh   512   // hidden
#define NWG  256   // workgroups
#define NTHR 512   // threads per WG
#define BH   128   // batch per WG (half)
#define KS   128   // K-slice per kq group

typedef unsigned int u32;

__device__ __forceinline__ float sigf(float x) { return 1.0f / (1.0f + __expf(-x)); }
__device__ __forceinline__ float tanhfast(float x) {
    float e = __expf(2.0f * x);
    return 1.0f - 2.0f / (e + 1.0f);
}

// Coherent (LLC-level) load/store: bypass non-coherent L1/L2 so no
// acquire-invalidate fence is ever needed -> weights stay hot in L2.
__device__ __forceinline__ float gload(const float* p) {
    return __hip_atomic_load(p, __ATOMIC_RELAXED, __HIP_MEMORY_SCOPE_AGENT);
}
__device__ __forceinline__ void gstore(float* p, float v) {
    __hip_atomic_store(p, v, __ATOMIC_RELAXED, __HIP_MEMORY_SCOPE_AGENT);
}

// WG (ug, bh): owns units j = 4*ug .. 4*ug+3 for batches bh*128 .. bh*128+127.
// Sweep role:  thread = (kq 0..3, bl 0..127): K-slice partial dot products.
// Finish role: thread = (u 0..3,  bl 0..127): reduce partials, gates, c-state.
// h layout: h[j][b] (4B), coalesced across bl. Custom half-grid barrier via
// phase-tagged flags (RELAXED/AGENT) — never invalidates L2.
__global__ void __launch_bounds__(NTHR, 2)
lstm_fused(const float* __restrict__ input,
           const float* __restrict__ l1_Wx, const float* __restrict__ l1_bx,
           const float* __restrict__ l1_Wh, const float* __restrict__ l1_bh,
           const float* __restrict__ l2_Wx, const float* __restrict__ l2_bx,
           const float* __restrict__ l2_Wh, const float* __restrict__ l2_bh,
           const float* __restrict__ fc1_W, const float* __restrict__ fc1_b,
           const float* __restrict__ fc2_W, const float* __restrict__ fc2_b,
           const float* __restrict__ fc3_W, const float* __restrict__ fc3_b,
           float* __restrict__ out, float* __restrict__ ws)
{
    cg::grid_group grid = cg::this_grid();
    const int wgid = blockIdx.x;
    const int ug = wgid >> 1;          // unit-group 0..127
    const int bh = wgid & 1;           // batch half 0..1
    const int tid = threadIdx.x;
    const int kq = tid >> 7;           // sweep role: K-quarter
    const int u  = tid >> 7;           // finish role: unit-in-group
    const int bl = tid & 127;          // local batch
    const int bg = bh * BH + bl;       // global batch
    const int jb = ug * 4;             // first owned unit

    float* h1A = ws;
    float* h1B = h1A + (size_t)Hh * Bb;
    float* h2A = h1B + (size_t)Hh * Bb;
    float* h2B = h2A + (size_t)Hh * Bb;
    u32*   flags = (u32*)(h2B + (size_t)Hh * Bb);   // [2][128]

    __shared__ float part[4][BH][33];   // K-partials, +1 pad (33) -> no bank conflicts
    __shared__ float hh[Hh];
    __shared__ float a1s[256];
    __shared__ float a2s[128];

    // 12 uniform weight bases (per matrix x gate); element [u][k] at [u*Hh + k].
    const float* W1g[4]; const float* W2xg[4]; const float* W2hg[4];
    #pragma unroll
    for (int g = 0; g < 4; ++g) {
        const size_t ro = (size_t)(g * Hh + jb) * Hh;
        W1g[g]  = l1_Wh + ro;
        W2xg[g] = l2_Wx + ro;
        W2hg[g] = l2_Wh + ro;
    }
    // finish-role per-unit gate rows
    const float* wx1g[4];
    float bias1[4], bias2[4];
    #pragma unroll
    for (int g = 0; g < 4; ++g) {
        const int row = g * Hh + jb + u;
        wx1g[g]  = l1_Wx + (size_t)row * INx;
        bias1[g] = l1_bx[row] + l1_bh[row];
        bias2[g] = l2_bx[row] + l2_bh[row];
    }

    // ---- init (plain stores; the single cg.sync below fences them) ----
    h2A[(size_t)(jb + u) * Bb + bg] = 0.0f;          // h2[-1] = 0
    if (tid == 0) flags[bh * 128 + ug] = 0;          // reset barrier flags (determinism)

    // prologue: h1[0] = gates(bias1 + x[0]·Wx) with h=0, c=0
    float c1, c2 = 0.0f;
    {
        const float* xr = input + (size_t)bg * Tt * INx;
        float a[4];
        #pragma unroll
        for (int g = 0; g < 4; ++g) {
            float acc = bias1[g];
            #pragma unroll
            for (int i = 0; i < INx; ++i) acc += xr[i] * wx1g[g][i];
            a[g] = acc;
        }
        const float ig = sigf(a[0]), gg = tanhfast(a[2]), og = sigf(a[3]);
        c1 = ig * gg;                                 // f*0 + i*g
        const float h1v = og * tanhfast(c1);
        h1A[(size_t)(jb + u) * Bb + bg] = h1v;
    }
    grid.sync();   // the ONLY runtime grid sync (also the only L2 invalidate)

    const float* h1c = h1A; float* h1n = h1B;
    const float* h2c = h2A; float* h2n = h2B;

    for (int t = 0; t < Tt; ++t) {
        // ---------- sweep: partial dots over this thread's K-slice ----------
        float a1[16], a2[16];
        #pragma unroll
        for (int r = 0; r < 16; ++r) { a1[r] = 0.0f; a2[r] = 0.0f; }

        const int k0 = kq * KS;
        #pragma unroll 4
        for (int kk = 0; kk < KS; ++kk) {
            const int k = k0 + kk;
            const float hv = gload(h1c + (size_t)k * Bb + bg);
            #pragma unroll
            for (int g = 0; g < 4; ++g) {
                #pragma unroll
                for (int uu = 0; uu < 4; ++uu) {
                    a1[uu * 4 + g] += hv * W1g[g][uu * Hh + k];   // L1 recurrent
                    a2[uu * 4 + g] += hv * W2xg[g][uu * Hh + k];  // L2 input
                }
            }
        }
        #pragma unroll 4
        for (int kk = 0; kk < KS; ++kk) {
            const int k = k0 + kk;
            const float hv = gload(h2c + (size_t)k * Bb + bg);
            #pragma unroll
            for (int g = 0; g < 4; ++g) {
                #pragma unroll
                for (int uu = 0; uu < 4; ++uu)
                    a2[uu * 4 + g] += hv * W2hg[g][uu * Hh + k];  // L2 recurrent
            }
        }
        #pragma unroll
        for (int r = 0; r < 16; ++r) {
            part[kq][bl][r]      = a1[r];
            part[kq][bl][16 + r] = a2[r];
        }
        __syncthreads();

        // ---------- finish: reduce + gates + state update ----------
        if (t < Tt - 1) {       // layer-1 step t+1
            float xv[INx];
            const float* xr = input + ((size_t)bg * Tt + (t + 1)) * INx;
            #pragma unroll
            for (int i = 0; i < INx; ++i) xv[i] = xr[i];
            float a[4];
            #pragma unroll
            for (int g = 0; g < 4; ++g) {
                float acc = bias1[g];
                #pragma unroll
                for (int q = 0; q < 4; ++q) acc += part[q][bl][u * 4 + g];
                #pragma unroll
                for (int i = 0; i < INx; ++i) acc += xv[i] * wx1g[g][i];
                a[g] = acc;
            }
            const float ig = sigf(a[0]), fg = sigf(a[1]), gg = tanhfast(a[2]), og = sigf(a[3]);
            c1 = fg * c1 + ig * gg;
            gstore(h1n + (size_t)(jb + u) * Bb + bg, og * tanhfast(c1));
        }
        {                        // layer-2 step t
            float a[4];
            #pragma unroll
            for (int g = 0; g < 4; ++g) {
                float acc = bias2[g];
                #pragma unroll
                for (int q = 0; q < 4; ++q) acc += part[q][bl][16 + u * 4 + g];
                a[g] = acc;
            }
            const float ig = sigf(a[0]), fg = sigf(a[1]), gg = tanhfast(a[2]), og = sigf(a[3]);
            c2 = fg * c2 + ig * gg;
            gstore(h2n + (size_t)(jb + u) * Bb + bg, og * tanhfast(c2));
        }

        // ---------- half-grid barrier (no L2 invalidate) ----------
        __syncthreads();   // drains each wave's vmem stores (vmcnt 0) before flag
        const u32 phase = (u32)(t + 1);
        if (tid == 0)
            __hip_atomic_store(&flags[bh * 128 + ug], phase,
                               __ATOMIC_RELEASE, __HIP_MEMORY_SCOPE_AGENT);
        if (tid < 128) {
            const u32* fp = &flags[bh * 128 + tid];
            while (__hip_atomic_load(fp, __ATOMIC_RELAXED, __HIP_MEMORY_SCOPE_AGENT) < phase)
                __builtin_amdgcn_s_sleep(2);
        }
        __syncthreads();

        // swap ping-pong buffers
        const float* tc;
        float* tn;
        tc = h1c; h1c = h1n; h1n = (float*)tc;
        tn = (float*)h2c; h2c = h2n; h2n = tn;
    }
    // final h2 is in h1?? no: in h2c (swapped after last iteration)

    // wait for BOTH halves before the FC head (cross-half reads below)
    if (tid < 256) {
        const u32* fp = &flags[tid];
        while (__hip_atomic_load(fp, __ATOMIC_RELAXED, __HIP_MEMORY_SCOPE_AGENT) < (u32)Tt)
            __builtin_amdgcn_s_sleep(2);
    }
    __syncthreads();

    // ---------- FC head: WG wgid handles batch wgid ----------
    hh[tid] = gload(h2c + (size_t)tid * Bb + wgid);   // h2_final[:, batch]
    __syncthreads();
    if (tid < 256) {
        float acc = fc1_b[tid];
        const float* wr = fc1_W + (size_t)tid * Hh;
        for (int i = 0; i < Hh; ++i) acc += wr[i] * hh[i];
        a1s[tid] = fmaxf(acc, 0.0f);
    }
    __syncthreads();
    if (tid < 128) {
        float acc = fc2_b[tid];
        const float* wr = fc2_W + (size_t)tid * 256;
        for (int i = 0; i < 256; ++i) acc += wr[i] * a1s[i];
        a2s[tid] = fmaxf(acc, 0.0f);
    }
    __syncthreads();
    if (tid == 0) {
        float acc = fc3_b[0];
        for (int i = 0; i < 128; ++i) acc += fc3_W[i] * a2s[i];
        out[wgid] = acc;
    }
}

extern "C" void kernel_launch(void* const* d_in, const int* in_sizes, int n_in,
                              void* d_out, int out_size, void* d_ws, size_t ws_size,
                              hipStream_t stream)
{
    (void)in_sizes; (void)n_in; (void)out_size; (void)ws_size;

    const float* input = (const float*)d_in[0];
    const float* l1_Wx = (const float*)d_in[1];
    const float* l1_bx = (const float*)d_in[2];
    const float* l1_Wh = (const float*)d_in[3];
    const float* l1_bh = (const float*)d_in[4];
    const float* l2_Wx = (const float*)d_in[5];
    const float* l2_bx = (const float*)d_in[6];
    const float* l2_Wh = (const float*)d_in[7];
    const float* l2_bh = (const float*)d_in[8];
    const float* fc1_W = (const float*)d_in[9];
    const float* fc1_b = (const float*)d_in[10];
    const float* fc2_W = (const float*)d_in[11];
    const float* fc2_b = (const float*)d_in[12];
    const float* fc3_W = (const float*)d_in[13];
    const float* fc3_b = (const float*)d_in[14];
    float* out = (float*)d_out;
    float* ws  = (float*)d_ws;

    void* args[] = {
        &input,
        &l1_Wx, &l1_bx, &l1_Wh, &l1_bh,
        &l2_Wx, &l2_bx, &l2_Wh, &l2_bh,
        &fc1_W, &fc1_b, &fc2_W, &fc2_b, &fc3_W, &fc3_b,
        &out, &ws
    };
    hipLaunchCooperativeKernel((void*)lstm_fused, dim3(NWG), dim3(NTHR), args, 0, stream);
}

// Round 4
// 34977.780 us; speedup vs baseline: 1.7200x; 1.5191x over previous
//
#include <hip/hip_runtime.h>
#include <hip/hip_cooperative_groups.h>

namespace cg = cooperative_groups;

#define Bb   256   // batch
#define Tt   512   // time steps
#define INx  19    // input features
#define Hh   512   // hidden
#define NWG  256   // workgroups (2 units each)
#define NTHR 512   // threads per WG: (ks 0..1) x (b 0..255)

typedef unsigned int u32;

__device__ __forceinline__ float sigf(float x) { return 1.0f / (1.0f + __expf(-x)); }
__device__ __forceinline__ float tanhfast(float x) {
    float e = __expf(2.0f * x);
    return 1.0f - 2.0f / (e + 1.0f);
}
// h stores bypass L1/L2 -> LLC (few per thread; reads stay cacheable)
__device__ __forceinline__ void gstore(float* p, float v) {
    __hip_atomic_store(p, v, __ATOMIC_RELAXED, __HIP_MEMORY_SCOPE_AGENT);
}

// Grid barrier without touching weight LDS: release own flag, poll all flags,
// then agent-acquire fence (buffer_inv) so cached h loads see fresh LLC data.
__device__ __forceinline__ void gbar(u32* flags, int wgid, int tid, u32 phase) {
    __syncthreads();   // drains all waves' vmem stores (vmcnt 0) before flag
    if (tid == 0)
        __hip_atomic_store(&flags[wgid], phase, __ATOMIC_RELEASE, __HIP_MEMORY_SCOPE_AGENT);
    if (tid < NWG) {
        while (__hip_atomic_load(&flags[tid], __ATOMIC_RELAXED, __HIP_MEMORY_SCOPE_AGENT) < phase)
            __builtin_amdgcn_s_sleep(2);
    }
    __syncthreads();
    __builtin_amdgcn_fence(__ATOMIC_ACQUIRE, "agent");   // buffer_inv: L1/L2 refetch
}

// One 8k block vs two weight row-groups (a1 += hb.W1, a2 += hb.W2)
__device__ __forceinline__ void fma_blk2(const float* __restrict__ w1b,
                                         const float* __restrict__ w2b,
                                         const float hb[8], float a1[8], float a2[8],
                                         int kk) {
    #pragma unroll
    for (int q = 0; q < 2; ++q) {
        #pragma unroll
        for (int rr = 0; rr < 8; ++rr) {
            const float4 w1 = *reinterpret_cast<const float4*>(&w1b[rr * Hh + kk + q * 4]);
            const float4 w2 = *reinterpret_cast<const float4*>(&w2b[rr * Hh + kk + q * 4]);
            a1[rr] += hb[q*4+0]*w1.x + hb[q*4+1]*w1.y + hb[q*4+2]*w1.z + hb[q*4+3]*w1.w;
            a2[rr] += hb[q*4+0]*w2.x + hb[q*4+1]*w2.y + hb[q*4+2]*w2.z + hb[q*4+3]*w2.w;
        }
    }
}
__device__ __forceinline__ void fma_blk1(const float* __restrict__ w3b,
                                         const float hb[8], float a2[8], int kk) {
    #pragma unroll
    for (int q = 0; q < 2; ++q) {
        #pragma unroll
        for (int rr = 0; rr < 8; ++rr) {
            const float4 w3 = *reinterpret_cast<const float4*>(&w3b[rr * Hh + kk + q * 4]);
            a2[rr] += hb[q*4+0]*w3.x + hb[q*4+1]*w3.y + hb[q*4+2]*w3.z + hb[q*4+3]*w3.w;
        }
    }
}

__global__ void __launch_bounds__(NTHR, 2)
lstm_fused(const float* __restrict__ input,
           const float* __restrict__ l1_Wx, const float* __restrict__ l1_bx,
           const float* __restrict__ l1_Wh, const float* __restrict__ l1_bh,
           const float* __restrict__ l2_Wx, const float* __restrict__ l2_bx,
           const float* __restrict__ l2_Wh, const float* __restrict__ l2_bh,
           const float* __restrict__ fc1_W, const float* __restrict__ fc1_b,
           const float* __restrict__ fc2_W, const float* __restrict__ fc2_b,
           const float* __restrict__ fc3_W, const float* __restrict__ fc3_b,
           float* __restrict__ out, float* __restrict__ ws)
{
    cg::grid_group grid = cg::this_grid();
    const int wgid = blockIdx.x;
    const int tid  = threadIdx.x;
    const int ks   = tid >> 8;      // K-half 0/1
    const int b    = tid & 255;     // batch
    const int jb   = wgid * 2;      // first owned unit

    float* h1A = ws;
    float* h1B = h1A + Hh * Bb;
    float* h2A = h1B + Hh * Bb;
    float* h2B = h2A + Hh * Bb;
    u32*   flags = (u32*)(h2B + Hh * Bb);

    // LDS: weights staged once (immune to L2 invalidates) + K-partial exchange
    __shared__ float wlds[24 * Hh];   // rows 0-7: l1_Wh, 8-15: l2_Wx, 16-23: l2_Wh  (48KB)
    __shared__ float part[Bb * 16];   // ks=0 partials (16KB); reused as FC scratch
    __shared__ float wx1l[8 * 20];    // l1_Wx rows, padded stride 20

    // ---- flag reset + the single runtime grid sync (fences resets) ----
    if (tid == 0)
        __hip_atomic_store(&flags[wgid], 0u, __ATOMIC_RELAXED, __HIP_MEMORY_SCOPE_AGENT);
    grid.sync();

    // ---- stage weights into LDS (once) ----
    for (int idx = tid; idx < 24 * Hh; idx += NTHR) {
        const int r = idx >> 9, k = idx & 511;
        const int rr = r & 7, u = rr >> 2, g = rr & 3;
        const float* src = (r < 8) ? l1_Wh : (r < 16) ? l2_Wx : l2_Wh;
        wlds[idx] = src[(size_t)(g * Hh + jb + u) * Hh + k];
    }
    if (tid < 8 * INx) {
        const int r = tid / INx, i = tid - r * INx;
        const int u = r >> 2, g = r & 3;
        wx1l[r * 20 + i] = l1_Wx[(size_t)(g * Hh + jb + u) * INx + i];
    }
    // biases into registers (held across the whole sequence)
    float b1r[8], b2r[8];
    #pragma unroll
    for (int rr = 0; rr < 8; ++rr) {
        const int u = rr >> 2, g = rr & 3;
        const int row = g * Hh + jb + u;
        b1r[rr] = l1_bx[row] + l1_bh[row];
        b2r[rr] = l2_bx[row] + l2_bh[row];
    }
    __syncthreads();

    const float* w1base = &wlds[0];
    const float* w2base = &wlds[8 * Hh];
    const float* w3base = &wlds[16 * Hh];

    float cc1[2] = {0.f, 0.f}, cc2[2] = {0.f, 0.f};

    const float* h1c = h1A; float* h1n = h1B;
    const float* h2c = h2A; float* h2n = h2B;

    // ---- prologue: h1[0] = gates(bias1 + x[0]·Wx1), h=0 ----
    if (ks == 1) {
        const float* xr = input + (size_t)b * Tt * INx;
        #pragma unroll
        for (int u = 0; u < 2; ++u) {
            float g4[4];
            #pragma unroll
            for (int g = 0; g < 4; ++g) {
                float acc = b1r[u * 4 + g];
                #pragma unroll
                for (int i = 0; i < INx; ++i) acc += xr[i] * wx1l[(u * 4 + g) * 20 + i];
                g4[g] = acc;
            }
            const float ig = sigf(g4[0]), gg = tanhfast(g4[2]), og = sigf(g4[3]);
            cc1[u] = ig * gg;                       // f*0 + i*g
            gstore(&h1A[(jb + u) * Bb + b], og * tanhfast(cc1[u]));
        }
    }
    gbar(flags, wgid, tid, 1u);

    // ---- main loop: iteration t computes h1[t+1] (t<511) and h2[t] ----
    for (int t = 0; t < Tt; ++t) {
        const bool doL1 = (t < Tt - 1);
        const bool doL2 = (t > 0);

        // prefetch x[t+1] early (consumed in finish phase)
        float xv[INx];
        if (ks == 1 && doL1) {
            const float* xr = input + ((size_t)b * Tt + (t + 1)) * INx;
            #pragma unroll
            for (int i = 0; i < INx; ++i) xv[i] = xr[i];
        }

        const int k0 = ks << 8;
        float a1[8], a2[8];
        #pragma unroll
        for (int r = 0; r < 8; ++r) { a1[r] = 0.f; a2[r] = 0.f; }

        // -------- sweep over h1[t] (K-half), 8-deep register prefetch --------
        float hb[8], hb2[8];
        #pragma unroll
        for (int j = 0; j < 8; ++j) hb[j] = h1c[(k0 + j) * Bb + b];
        if (doL2) {   // issue first h2 block early too
            #pragma unroll
            for (int j = 0; j < 8; ++j) hb2[j] = h2c[(k0 + j) * Bb + b];
        }
        for (int kb = 0; kb < 31; ++kb) {
            const int kk = k0 + (kb << 3);
            float hn[8];
            #pragma unroll
            for (int j = 0; j < 8; ++j) hn[j] = h1c[(kk + 8 + j) * Bb + b];
            fma_blk2(w1base, w2base, hb, a1, a2, kk);
            #pragma unroll
            for (int j = 0; j < 8; ++j) hb[j] = hn[j];
        }
        fma_blk2(w1base, w2base, hb, a1, a2, k0 + 248);

        // -------- sweep over h2[t-1] (K-half) --------
        if (doL2) {
            for (int kb = 0; kb < 31; ++kb) {
                const int kk = k0 + (kb << 3);
                float hn[8];
                #pragma unroll
                for (int j = 0; j < 8; ++j) hn[j] = h2c[(kk + 8 + j) * Bb + b];
                fma_blk1(w3base, hb2, a2, kk);
                #pragma unroll
                for (int j = 0; j < 8; ++j) hb2[j] = hn[j];
            }
            fma_blk1(w3base, hb2, a2, k0 + 248);
        }

        // -------- exchange K-partials --------
        if (ks == 0) {
            *reinterpret_cast<float4*>(&part[b * 16 + 0])  = make_float4(a1[0], a1[1], a1[2], a1[3]);
            *reinterpret_cast<float4*>(&part[b * 16 + 4])  = make_float4(a1[4], a1[5], a1[6], a1[7]);
            *reinterpret_cast<float4*>(&part[b * 16 + 8])  = make_float4(a2[0], a2[1], a2[2], a2[3]);
            *reinterpret_cast<float4*>(&part[b * 16 + 12]) = make_float4(a2[4], a2[5], a2[6], a2[7]);
        }
        __syncthreads();

        // -------- finish: gates + state update (ks==1 threads) --------
        if (ks == 1) {
            const float4 p0 = *reinterpret_cast<const float4*>(&part[b * 16 + 0]);
            const float4 p1 = *reinterpret_cast<const float4*>(&part[b * 16 + 4]);
            const float4 p2 = *reinterpret_cast<const float4*>(&part[b * 16 + 8]);
            const float4 p3 = *reinterpret_cast<const float4*>(&part[b * 16 + 12]);
            a1[0] += p0.x; a1[1] += p0.y; a1[2] += p0.z; a1[3] += p0.w;
            a1[4] += p1.x; a1[5] += p1.y; a1[6] += p1.z; a1[7] += p1.w;
            a2[0] += p2.x; a2[1] += p2.y; a2[2] += p2.z; a2[3] += p2.w;
            a2[4] += p3.x; a2[5] += p3.y; a2[6] += p3.z; a2[7] += p3.w;

            if (doL1) {
                #pragma unroll
                for (int u = 0; u < 2; ++u) {
                    float g4[4];
                    #pragma unroll
                    for (int g = 0; g < 4; ++g) {
                        float acc = a1[u * 4 + g] + b1r[u * 4 + g];
                        #pragma unroll
                        for (int i = 0; i < INx; ++i) acc += xv[i] * wx1l[(u * 4 + g) * 20 + i];
                        g4[g] = acc;
                    }
                    const float ig = sigf(g4[0]), fg = sigf(g4[1]);
                    const float gg = tanhfast(g4[2]), og = sigf(g4[3]);
                    cc1[u] = fg * cc1[u] + ig * gg;
                    gstore(&h1n[(jb + u) * Bb + b], og * tanhfast(cc1[u]));
                }
            }
            #pragma unroll
            for (int u = 0; u < 2; ++u) {
                const float ig = sigf(a2[u * 4 + 0] + b2r[u * 4 + 0]);
                const float fg = sigf(a2[u * 4 + 1] + b2r[u * 4 + 1]);
                const float gg = tanhfast(a2[u * 4 + 2] + b2r[u * 4 + 2]);
                const float og = sigf(a2[u * 4 + 3] + b2r[u * 4 + 3]);
                cc2[u] = fg * cc2[u] + ig * gg;
                gstore(&h2n[(jb + u) * Bb + b], og * tanhfast(cc2[u]));
            }
        }

        gbar(flags, wgid, tid, (u32)(t + 2));

        const float* tp = h1c; h1c = h1n; h1n = (float*)tp;
        tp = h2c; h2c = h2n; h2n = (float*)tp;
    }
    // final h2 now in h2c

    // ---------- FC head: WG wgid handles batch wgid; reuse `part` LDS ----------
    float* hh  = part;            // 512
    float* a1s = part + Hh;       // 256
    float* a2s = part + Hh + 256; // 128
    hh[tid] = h2c[tid * Bb + wgid];
    __syncthreads();
    if (tid < 256) {
        float acc = fc1_b[tid];
        const float* wr = fc1_W + (size_t)tid * Hh;
        for (int i = 0; i < Hh; ++i) acc += wr[i] * hh[i];
        a1s[tid] = fmaxf(acc, 0.0f);
    }
    __syncthreads();
    if (tid < 128) {
        float acc = fc2_b[tid];
        const float* wr = fc2_W + (size_t)tid * 256;
        for (int i = 0; i < 256; ++i) acc += wr[i] * a1s[i];
        a2s[tid] = fmaxf(acc, 0.0f);
    }
    __syncthreads();
    if (tid == 0) {
        float acc = fc3_b[0];
        for (int i = 0; i < 128; ++i) acc += fc3_W[i] * a2s[i];
        out[wgid] = acc;
    }
}

extern "C" void kernel_launch(void* const* d_in, const int* in_sizes, int n_in,
                              void* d_out, int out_size, void* d_ws, size_t ws_size,
                              hipStream_t stream)
{
    (void)in_sizes; (void)n_in; (void)out_size; (void)ws_size;

    const float* input = (const float*)d_in[0];
    const float* l1_Wx = (const float*)d_in[1];
    const float* l1_bx = (const float*)d_in[2];
    const float* l1_Wh = (const float*)d_in[3];
    const float* l1_bh = (const float*)d_in[4];
    const float* l2_Wx = (const float*)d_in[5];
    const float* l2_bx = (const float*)d_in[6];
    const float* l2_Wh = (const float*)d_in[7];
    const float* l2_bh = (const float*)d_in[8];
    const float* fc1_W = (const float*)d_in[9];
    const float* fc1_b = (const float*)d_in[10];
    const float* fc2_W = (const float*)d_in[11];
    const float* fc2_b = (const float*)d_in[12];
    const float* fc3_W = (const float*)d_in[13];
    const float* fc3_b = (const float*)d_in[14];
    float* out = (float*)d_out;
    float* ws  = (float*)d_ws;

    void* args[] = {
        &input,
        &l1_Wx, &l1_bx, &l1_Wh, &l1_bh,
        &l2_Wx, &l2_bx, &l2_Wh, &l2_bh,
        &fc1_W, &fc1_b, &fc2_W, &fc2_b, &fc3_W, &fc3_b,
        &out, &ws
    };
    hipLaunchCooperativeKernel((void*)lstm_fused, dim3(NWG), dim3(NTHR), args, 0, stream);
}